// Round 1
// baseline (9320.803 us; speedup 1.0000x reference)
//
#include <hip/hip_runtime.h>

#define B_ 64
#define T_ 383
#define S_ 384
#define ENC_ 768
#define TAGD_ 128
#define D_ 896
#define HG_ 400
#define HE_ 256
#define MSTEP_ 20
#define RTOT_ (B_*S_)                    // 24576
#define HEAD_SZ_ ((size_t)RTOT_*TAGD_)   // 3145728

typedef short short8 __attribute__((ext_vector_type(8)));
typedef float f32x4 __attribute__((ext_vector_type(4)));

__device__ __forceinline__ float bf2f(unsigned short u){
  union { unsigned int i; float f; } v; v.i = ((unsigned int)u) << 16; return v.f;
}
__device__ __forceinline__ float lo_f(unsigned int u){
  union { unsigned int i; float f; } v; v.i = u << 16; return v.f;
}
__device__ __forceinline__ float hi_f(unsigned int u){
  union { unsigned int i; float f; } v; v.i = u & 0xffff0000u; return v.f;
}
__device__ __forceinline__ unsigned short f2bf(float f){
  union { float f; unsigned int i; } v; v.f = f;
  unsigned int r = (v.i + 0x7fffu + ((v.i >> 16) & 1u)) >> 16;
  return (unsigned short)r;
}
__device__ __forceinline__ float tanh_fast(float x){
  float xc = fminf(fmaxf(x, -15.f), 15.f);
  float e = __expf(2.f*xc);
  return (e - 1.f) / (e + 1.f);
}

// ---------------------------------------------------------------------------
// Runtime MFMA C/D-layout discovery (probe MFMAs) — used by the GEMM kernels.
// ---------------------------------------------------------------------------
__device__ __forceinline__ void probe_maps(int lane, int* mlab, int* nlab){
  unsigned short lb = f2bf((float)(lane & 15));
  short8 av, bv;
  #pragma unroll
  for (int j = 0; j < 8; j++){ av[j] = (short)lb; bv[j] = (short)0x3F80; } // bf16(1.0)
  f32x4 z = {0.f,0.f,0.f,0.f};
  f32x4 d1 = __builtin_amdgcn_mfma_f32_16x16x32_bf16(av, bv, z, 0, 0, 0);
  f32x4 d2 = __builtin_amdgcn_mfma_f32_16x16x32_bf16(bv, av, z, 0, 0, 0);
  #pragma unroll
  for (int i = 0; i < 4; i++){
    mlab[i] = (int)(d1[i]*0.03125f + 0.5f);
    nlab[i] = (int)(d2[i]*0.03125f + 0.5f);
  }
}

// Generic float -> bf16 (n multiple of 4)
__global__ __launch_bounds__(256) void cvt4(const float* __restrict__ src,
                                            unsigned short* __restrict__ dst, int n4)
{
  int i = blockIdx.x*256 + threadIdx.x;
  if (i >= n4) return;
  float4 v = ((const float4*)src)[i];
  ((ushort4*)dst)[i] = make_ushort4(f2bf(v.x), f2bf(v.y), f2bf(v.z), f2bf(v.w));
}

// ---------------------------------------------------------------------------
// Pack Whh_f / Whh_b into the RNN MFMA B-layout:
// Wrnn[dir][n][k], n in [0,416) (rows >=400 zero), k in [0,800),
// with the bf16 weight DUPLICATED pairwise: k=2m and k=2m+1 both = bf16(W[n][m]).
// This pairs with the hi/lo-interleaved H so that
//   sum_k A[b][k]*B[n][k] = sum_m (hi_m + lo_m) * W[n][m]  (f32-accurate h).
// ---------------------------------------------------------------------------
__global__ __launch_bounds__(256) void pack_wrnn(const float* __restrict__ Wf,
                                                 const float* __restrict__ Wb,
                                                 unsigned int* __restrict__ Wr)
{
  int idx = blockIdx.x*256 + threadIdx.x;
  if (idx >= 2*416*400) return;
  int dir = idx / (416*400);
  int rem = idx % (416*400);
  int n = rem / 400, m = rem % 400;
  unsigned short v = 0;
  if (n < HG_){
    const float* W = dir ? Wb : Wf;
    v = f2bf(W[(size_t)n*HG_ + m]);
  }
  Wr[idx] = (unsigned int)v | ((unsigned int)v << 16);
}

// ---------------------------------------------------------------------------
// pre[r][n] (n<400: fwd, else bwd) = X[r].Wihcat[n] + bih[n] + bhh[n], bf16 out.
// ---------------------------------------------------------------------------
__global__ __launch_bounds__(256) void gemm_pre(
    const float* __restrict__ inp, const float* __restrict__ tag,
    const float* __restrict__ sent, const unsigned short* __restrict__ W,
    const float* __restrict__ bihf, const float* __restrict__ bhhf,
    const float* __restrict__ bihb, const float* __restrict__ bhhb,
    unsigned short* __restrict__ preb)
{
  int wid = blockIdx.x*4 + (threadIdx.x >> 6);
  int lane = threadIdx.x & 63;
  int q = lane >> 4, l16 = lane & 15;
  int mt = wid / 25, ct = wid % 25;
  int r = mt*16 + l16;
  int s = r % S_, b = r / S_;
  int mlab[4], nlab[4];
  probe_maps(lane, mlab, nlab);
  int n0 = ct*32 + l16, n1 = n0 + 16;
  const unsigned short* w0 = W + (size_t)n0*D_;
  const unsigned short* w1 = W + (size_t)n1*D_;
  f32x4 acc0 = {0.f,0.f,0.f,0.f}, acc1 = {0.f,0.f,0.f,0.f};
  for (int k0 = 0; k0 < D_; k0 += 32){
    int k = k0 + q*8;   // 8-float group never straddles the 768 boundary
    const float* asrc = (s == 0) ? (sent + k)
        : ((k < ENC_) ? inp + (size_t)(b*T_ + (s-1))*ENC_ + k
                      : tag + (size_t)(b*T_ + (s-1))*TAGD_ + (k - ENC_));
    float4 v0 = *(const float4*)asrc;
    float4 v1 = *(const float4*)(asrc + 4);
    short8 a;
    a[0]=(short)f2bf(v0.x); a[1]=(short)f2bf(v0.y); a[2]=(short)f2bf(v0.z); a[3]=(short)f2bf(v0.w);
    a[4]=(short)f2bf(v1.x); a[5]=(short)f2bf(v1.y); a[6]=(short)f2bf(v1.z); a[7]=(short)f2bf(v1.w);
    acc0 = __builtin_amdgcn_mfma_f32_16x16x32_bf16(a, *(const short8*)(w0 + k), acc0, 0,0,0);
    acc1 = __builtin_amdgcn_mfma_f32_16x16x32_bf16(a, *(const short8*)(w1 + k), acc1, 0,0,0);
  }
  #pragma unroll
  for (int i = 0; i < 4; i++){
    int row = mt*16 + mlab[i];
    int c0 = ct*32 + nlab[i], c1 = c0 + 16;
    float bb0 = (c0 < HG_) ? (bihf[c0] + bhhf[c0]) : (bihb[c0-HG_] + bhhb[c0-HG_]);
    float bb1 = (c1 < HG_) ? (bihf[c1] + bhhf[c1]) : (bihb[c1-HG_] + bhhb[c1-HG_]);
    preb[(size_t)row*800 + c0] = f2bf(acc0[i] + bb0);
    preb[(size_t)row*800 + c1] = f2bf(acc1[i] + bb1);
  }
}

// ---------------------------------------------------------------------------
// Batched masked RNN via MFMA.
// 8 blocks = 2 dirs x 4 batch-groups of 16. Block = 4 waves (256 thr).
// Per step: H_new(16x400) = tanh(pre + H_old @ Whh^T) with mask blend.
// H kept in LDS as hi/lo bf16 pairs (k = 2m interleave, K=800) so the
// recurrence carries ~f32 precision. Ping-pong buffers, 1 barrier/step.
// N padded to 416 -> 26 n-tiles; waves take 7 tiles each (tiles >=25 dead).
// ---------------------------------------------------------------------------
#define RK_ 800
#define RSTR_ 808   // shorts per H row (800 + 8 pad; stride 404 dwords -> 2-way banks)
__global__ __launch_bounds__(256, 1) void rnn_mfma(
    const unsigned short* __restrict__ preb, const unsigned short* __restrict__ Wrnn,
    const int* __restrict__ mask, unsigned short* __restrict__ gs)
{
  __shared__ __align__(16) unsigned short H[2][16][RSTR_];
  int tid = threadIdx.x;
  int wave = tid >> 6, lane = tid & 63, q = lane >> 4, l16 = lane & 15;
  int dir = blockIdx.x >> 2, bg = blockIdx.x & 3;
  int nt0 = wave * 7;          // tiles nt0..nt0+6; tiles >= 25 are dead (n >= 400)
  int b0 = bg * 16;
  const unsigned short* Wd = Wrnn + (size_t)dir * 416 * RK_;

  for (int i = tid; i < 2*16*(RSTR_/2); i += 256) ((unsigned int*)H)[i] = 0u;

  // per-tile B base pointers (row-clamped for out-of-range tiles)
  const unsigned short* wb[7];
  #pragma unroll
  for (int j = 0; j < 7; j++){
    int rw = (nt0 + j) * 16 + l16;
    if (rw > 415) rw = 0;
    wb[j] = Wd + (size_t)rw * RK_ + q * 8;
  }
  __syncthreads();

  for (int stp = 0; stp < S_; stp++){
    int t = dir ? (S_ - 1 - stp) : stp;
    int cur = stp & 1, nxt = cur ^ 1;

    // A fragments: row = batch-in-group (l16), k = hi/lo interleaved hidden dim
    short8 af[25];
    #pragma unroll
    for (int kt = 0; kt < 25; kt++)
      af[kt] = *(const short8*)&H[cur][l16][kt*32 + q*8];

    float mv[4];
    #pragma unroll
    for (int ri = 0; ri < 4; ri++){
      int b = b0 + q*4 + ri;
      mv[ri] = (t > 0) ? (float)mask[b*T_ + (t-1)] : 1.f;
    }

    // prefetch pre + h_old for this lane's C fragment (rows q*4+ri, col n)
    float pr[7][4]; unsigned int hu[7][4];
    #pragma unroll
    for (int j = 0; j < 7; j++){
      bool live = (nt0 + j) < 25;
      int n = (nt0 + j)*16 + l16;
      #pragma unroll
      for (int ri = 0; ri < 4; ri++){
        int b = b0 + q*4 + ri;
        if (live){
          pr[j][ri] = bf2f(preb[(size_t)(b*S_ + t)*800 + dir*HG_ + n]);
          hu[j][ri] = *(const unsigned int*)&H[cur][q*4 + ri][2*n];
        } else { pr[j][ri] = 0.f; hu[j][ri] = 0u; }
      }
    }

    // 7 independent accumulator chains, interleaved over kt for ILP
    f32x4 acc[7];
    #pragma unroll
    for (int j = 0; j < 7; j++) acc[j] = (f32x4){0.f,0.f,0.f,0.f};
    #pragma unroll
    for (int kt = 0; kt < 25; kt++){
      #pragma unroll
      for (int j = 0; j < 7; j++)
        acc[j] = __builtin_amdgcn_mfma_f32_16x16x32_bf16(af[kt], *(const short8*)(wb[j] + kt*32), acc[j], 0,0,0);
    }

    // epilogue: tanh, mask blend, hi/lo re-split, gs store
    #pragma unroll
    for (int j = 0; j < 7; j++){
      if ((nt0 + j) < 25){
        int n = (nt0 + j)*16 + l16;
        #pragma unroll
        for (int ri = 0; ri < 4; ri++){
          int b = b0 + q*4 + ri;
          float hn = tanh_fast(acc[j][ri] + pr[j][ri]);
          unsigned int u = hu[j][ri];
          float hold = bf2f((unsigned short)(u & 0xffffu)) + bf2f((unsigned short)(u >> 16));
          float hnew = mv[ri]*hn + (1.f - mv[ri])*hold;
          unsigned short hi = f2bf(hnew);
          unsigned short lo = f2bf(hnew - bf2f(hi));
          *(unsigned int*)&H[nxt][q*4 + ri][2*n] = (unsigned int)hi | ((unsigned int)lo << 16);
          gs[(size_t)(b*S_ + t)*800 + dir*HG_ + n] = f2bf(hnew * mv[ri]);
        }
      }
    }
    __syncthreads();   // writes to H[nxt] visible before next step's reads
  }
}

// ---------------------------------------------------------------------------
// proj[r][n] = gs[r] . Wg2e[n] + bg2e[n]   (K=800, N=256), fp32 out
// ---------------------------------------------------------------------------
__global__ __launch_bounds__(256) void gemm_proj(
    const unsigned short* __restrict__ gs, const unsigned short* __restrict__ Wg2e,
    const float* __restrict__ bg2e, float* __restrict__ proj)
{
  int wid = blockIdx.x*4 + (threadIdx.x >> 6);
  int lane = threadIdx.x & 63;
  int q = lane >> 4, l16 = lane & 15;
  int mt = wid >> 3, ct = wid & 7;
  int mlab[4], nlab[4];
  probe_maps(lane, mlab, nlab);
  const unsigned short* arow = gs + (size_t)(mt*16 + l16)*800;
  int n0 = ct*32 + l16, n1 = n0 + 16;
  const unsigned short* w0 = Wg2e + (size_t)n0*800;
  const unsigned short* w1 = Wg2e + (size_t)n1*800;
  f32x4 acc0 = {0.f,0.f,0.f,0.f}, acc1 = {0.f,0.f,0.f,0.f};
  for (int k0 = 0; k0 < 800; k0 += 32){
    int k = k0 + q*8;
    short8 a = *(const short8*)(arow + k);
    acc0 = __builtin_amdgcn_mfma_f32_16x16x32_bf16(a, *(const short8*)(w0 + k), acc0, 0,0,0);
    acc1 = __builtin_amdgcn_mfma_f32_16x16x32_bf16(a, *(const short8*)(w1 + k), acc1, 0,0,0);
  }
  #pragma unroll
  for (int i = 0; i < 4; i++){
    int row = mt*16 + mlab[i];
    int c0 = ct*32 + nlab[i], c1 = c0 + 16;
    proj[(size_t)row*HE_ + c0] = acc0[i] + bg2e[c0];
    proj[(size_t)row*HE_ + c1] = acc1[i] + bg2e[c1];
  }
}

// ---------------------------------------------------------------------------
// head_tag / dep_tag = elu(gs @ Wtag^T + b), N=256 (c<128 head, else dep).
// ---------------------------------------------------------------------------
__global__ __launch_bounds__(256) void gemm_tag(
    const unsigned short* __restrict__ gs, const unsigned short* __restrict__ Wtag,
    const float* __restrict__ bht, const float* __restrict__ bdt,
    float* __restrict__ outH)
{
  int wid = blockIdx.x*4 + (threadIdx.x >> 6);
  int lane = threadIdx.x & 63;
  int q = lane >> 4, l16 = lane & 15;
  int mt = wid >> 3, ct = wid & 7;
  int mlab[4], nlab[4];
  probe_maps(lane, mlab, nlab);
  const unsigned short* arow = gs + (size_t)(mt*16 + l16)*800;
  int n0 = ct*32 + l16, n1 = n0 + 16;
  const unsigned short* w0 = Wtag + (size_t)n0*800;
  const unsigned short* w1 = Wtag + (size_t)n1*800;
  f32x4 acc0 = {0.f,0.f,0.f,0.f}, acc1 = {0.f,0.f,0.f,0.f};
  for (int k0 = 0; k0 < 800; k0 += 32){
    int k = k0 + q*8;
    short8 a = *(const short8*)(arow + k);
    acc0 = __builtin_amdgcn_mfma_f32_16x16x32_bf16(a, *(const short8*)(w0 + k), acc0, 0,0,0);
    acc1 = __builtin_amdgcn_mfma_f32_16x16x32_bf16(a, *(const short8*)(w1 + k), acc1, 0,0,0);
  }
  #pragma unroll
  for (int i = 0; i < 4; i++){
    int row = mt*16 + mlab[i];
    int c0 = ct*32 + nlab[i], c1 = c0 + 16;
    float v0 = acc0[i] + ((c0 < TAGD_) ? bht[c0] : bdt[c0-TAGD_]);
    float v1 = acc1[i] + ((c1 < TAGD_) ? bht[c1] : bdt[c1-TAGD_]);
    v0 = (v0 > 0.f) ? v0 : expm1f(v0);
    v1 = (v1 > 0.f) ? v1 : expm1f(v1);
    if (c0 < TAGD_) outH[(size_t)row*TAGD_ + c0] = v0;
    else            outH[HEAD_SZ_ + (size_t)row*TAGD_ + (c0-TAGD_)] = v0;
    if (c1 < TAGD_) outH[(size_t)row*TAGD_ + c1] = v1;
    else            outH[HEAD_SZ_ + (size_t)row*TAGD_ + (c1-TAGD_)] = v1;
  }
}

// ---------------------------------------------------------------------------
// estep scan, register-resident WhhE.
// 256 blocks x 4 waves, 96 rows/block (24576 = 256*96, one full-GPU round).
// Each wave owns a 64-col slice of WhhE in 128 VGPRs (loaded once) plus
// per-column bias/Wcls/WihE constants -> zero global loads in the step loop.
// H ping-pongs in LDS (stride 264 shorts: 2-way bank aliasing, free).
// Logit reduction: shfl_xor butterfly over the 16-lane col groups + 4-slot
// staged LDS sum (replaces 16-way-contended LDS atomics).
// ---------------------------------------------------------------------------
#define EROWS_ 96
#define ESTR_ 264
__global__ __launch_bounds__(256, 1) void estep2(
    const float* __restrict__ proj, const unsigned short* __restrict__ WhhE,
    const float* __restrict__ bihE, const float* __restrict__ bhhE,
    const float* __restrict__ WihE, const float* __restrict__ Wcls,
    const float* __restrict__ bclsp, const float* __restrict__ bosp,
    float* __restrict__ Ap)
{
  __shared__ __align__(16) unsigned short H[2][EROWS_][ESTR_];
  __shared__ float lacc[4][EROWS_];
  __shared__ float xls[EROWS_];
  int tid = threadIdx.x;
  int wave = tid >> 6, lane = tid & 63, q = lane >> 4, l16 = lane & 15;
  size_t rowbase = (size_t)blockIdx.x * EROWS_;

  // persistent B fragments + per-col constants (col n = wave*64 + nt*16 + l16)
  short8 bw[4][8];
  float bias_n[4], wcl_n[4], wih_n[4];
  #pragma unroll
  for (int nt = 0; nt < 4; nt++){
    int n = wave*64 + nt*16 + l16;
    #pragma unroll
    for (int kt = 0; kt < 8; kt++)
      bw[nt][kt] = *(const short8*)(WhhE + (size_t)n*HE_ + kt*32 + q*8);
    bias_n[nt] = bihE[n] + bhhE[n];
    wcl_n[nt]  = Wcls[n];
    wih_n[nt]  = WihE[n];
  }
  for (int i = tid; i < EROWS_*HE_; i += 256){
    int r = i >> 8, n = i & 255;
    H[0][r][n] = f2bf(proj[(rowbase + r)*HE_ + n]);
  }
  if (tid < EROWS_) xls[tid] = bosp[0];
  float bc = bclsp[0];
  __syncthreads();

  for (int stp = 0; stp < MSTEP_; stp++){
    int cur = stp & 1, nxt = cur ^ 1;
    float lp[6][4];
    #pragma unroll
    for (int mt = 0; mt < 6; mt++){
      short8 af[8];
      #pragma unroll
      for (int kt = 0; kt < 8; kt++)
        af[kt] = *(const short8*)&H[cur][mt*16 + l16][kt*32 + q*8];
      float xr[4];
      #pragma unroll
      for (int ri = 0; ri < 4; ri++) xr[ri] = xls[mt*16 + q*4 + ri];
      f32x4 acc[4];
      #pragma unroll
      for (int nt = 0; nt < 4; nt++) acc[nt] = (f32x4){0.f,0.f,0.f,0.f};
      #pragma unroll
      for (int kt = 0; kt < 8; kt++){
        #pragma unroll
        for (int nt = 0; nt < 4; nt++)
          acc[nt] = __builtin_amdgcn_mfma_f32_16x16x32_bf16(af[kt], bw[nt][kt], acc[nt], 0,0,0);
      }
      #pragma unroll
      for (int ri = 0; ri < 4; ri++) lp[mt][ri] = 0.f;
      #pragma unroll
      for (int nt = 0; nt < 4; nt++){
        int n = wave*64 + nt*16 + l16;
        #pragma unroll
        for (int ri = 0; ri < 4; ri++){
          float v = acc[nt][ri] + bias_n[nt] + xr[ri]*wih_n[nt];
          float h = tanh_fast(v);
          lp[mt][ri] += h * wcl_n[nt];
          H[nxt][mt*16 + q*4 + ri][n] = f2bf(h);
        }
      }
    }
    // reduce partial logits over the 16 col-lanes of each q group
    #pragma unroll
    for (int mt = 0; mt < 6; mt++){
      #pragma unroll
      for (int ri = 0; ri < 4; ri++){
        float v = lp[mt][ri];
        v += __shfl_xor(v, 1, 16);
        v += __shfl_xor(v, 2, 16);
        v += __shfl_xor(v, 4, 16);
        v += __shfl_xor(v, 8, 16);
        lp[mt][ri] = v;
      }
    }
    if (l16 == 0){
      #pragma unroll
      for (int mt = 0; mt < 6; mt++)
        #pragma unroll
        for (int ri = 0; ri < 4; ri++)
          lacc[wave][mt*16 + q*4 + ri] = lp[mt][ri];
    }
    __syncthreads();
    if (tid < EROWS_){
      float lg = lacc[0][tid] + lacc[1][tid] + lacc[2][tid] + lacc[3][tid] + bc;
      Ap[(rowbase + tid)*MSTEP_ + stp] = lg;
      xls[tid] = lg;
    }
    __syncthreads();
  }
}

// ---------------------------------------------------------------------------
// arc_logits band gather -> float32
// ---------------------------------------------------------------------------
__global__ __launch_bounds__(256) void band_kernel(const float* __restrict__ Ap,
                                                   float* __restrict__ arc)
{
  int idx = blockIdx.x*256 + threadIdx.x;
  int c = idx % S_;
  int rr = (idx / S_) % S_;
  int b = idx / (S_*S_);
  int start = rr - MSTEP_; if (start < 0) start = 0;
  bool valid = (c >= start) && (c < rr);
  float v = 0.f;
  if (valid) v = Ap[(size_t)(b*S_ + rr)*MSTEP_ + (c - start)];
  arc[idx] = v;
}

// ---------------------------------------------------------------------------
extern "C" void kernel_launch(void* const* d_in, const int* in_sizes, int n_in,
                              void* d_out, int out_size, void* d_ws, size_t ws_size,
                              hipStream_t stream)
{
  const float* inp  = (const float*)d_in[0];
  const float* tag  = (const float*)d_in[1];
  const int*   mask = (const int*)d_in[2];
  const float* sent = (const float*)d_in[3];
  const float* Wihf = (const float*)d_in[4];
  const float* Whhf = (const float*)d_in[5];
  const float* bihf = (const float*)d_in[6];
  const float* bhhf = (const float*)d_in[7];
  const float* Wihb = (const float*)d_in[8];
  const float* Whhb = (const float*)d_in[9];
  const float* bihb = (const float*)d_in[10];
  const float* bhhb = (const float*)d_in[11];
  const float* Wg2e = (const float*)d_in[12];
  const float* bg2e = (const float*)d_in[13];
  const float* WihE = (const float*)d_in[14];
  const float* WhhE = (const float*)d_in[15];
  const float* bihE = (const float*)d_in[16];
  const float* bhhE = (const float*)d_in[17];
  const float* Wcls = (const float*)d_in[18];
  const float* bcls = (const float*)d_in[19];
  const float* bos  = (const float*)d_in[20];
  const float* Wht  = (const float*)d_in[21];
  const float* bht  = (const float*)d_in[22];
  const float* Wdt  = (const float*)d_in[23];
  const float* bdt  = (const float*)d_in[24];
  (void)in_sizes; (void)n_in; (void)out_size; (void)ws_size;

  char* ws = (char*)d_ws;
  unsigned short* preb   = (unsigned short*)ws;                       // 39,321,600 B
  unsigned short* gs     = (unsigned short*)(ws + 39321600);          // 39,321,600 B
  unsigned short* Wrnn   = (unsigned short*)(ws + 78643200);          //  1,331,200 B
  unsigned short* Wihcat = (unsigned short*)(ws + 79974400);          //  1,433,600 B
  unsigned short* Wg2e_b = (unsigned short*)(ws + 81408000);          //    409,600 B
  unsigned short* Wtag_b = (unsigned short*)(ws + 81817600);          //    409,600 B
  unsigned short* WhhE_b = (unsigned short*)(ws + 82227200);          //    131,072 B (end ~82.4 MB)
  // preb is dead after rnn_mfma; proj/Ap alias into it.
  float*          proj   = (float*)ws;                                // 25,165,824 B (alias)
  float*          Ap     = (float*)(ws + 25165824);                   //  1,966,080 B (alias)

  float* outH   = (float*)d_out;                 // f32: reference output dtype
  float* outArc = outH + 2*HEAD_SZ_;

  hipLaunchKernelGGL(cvt4, dim3(350), dim3(256), 0, stream, Wihf, Wihcat,           400*896/4);
  hipLaunchKernelGGL(cvt4, dim3(350), dim3(256), 0, stream, Wihb, Wihcat + 400*896, 400*896/4);
  hipLaunchKernelGGL(cvt4, dim3(200), dim3(256), 0, stream, Wg2e, Wg2e_b,           256*800/4);
  hipLaunchKernelGGL(cvt4, dim3(100), dim3(256), 0, stream, Wht,  Wtag_b,           128*800/4);
  hipLaunchKernelGGL(cvt4, dim3(100), dim3(256), 0, stream, Wdt,  Wtag_b + 128*800, 128*800/4);
  hipLaunchKernelGGL(cvt4, dim3(64),  dim3(256), 0, stream, WhhE, WhhE_b,           256*256/4);
  hipLaunchKernelGGL(pack_wrnn, dim3(1300), dim3(256), 0, stream, Whhf, Whhb, (unsigned int*)Wrnn);
  hipLaunchKernelGGL(gemm_pre, dim3(9600), dim3(256), 0, stream,
                     inp, tag, sent, Wihcat, bihf, bhhf, bihb, bhhb, preb);
  hipLaunchKernelGGL(rnn_mfma, dim3(8), dim3(256), 0, stream, preb, Wrnn, mask, gs);
  hipLaunchKernelGGL(gemm_proj, dim3(3072), dim3(256), 0, stream, gs, Wg2e_b, bg2e, proj);
  hipLaunchKernelGGL(gemm_tag,  dim3(3072), dim3(256), 0, stream, gs, Wtag_b, bht, bdt, outH);
  hipLaunchKernelGGL(estep2, dim3(256), dim3(256), 0, stream,
                     proj, WhhE_b, bihE, bhhE, WihE, Wcls, bcls, bos, Ap);
  hipLaunchKernelGGL(band_kernel, dim3(36864), dim3(256), 0, stream, Ap, outArc);
}